// Round 8
// baseline (104.072 us; speedup 1.0000x reference)
//
#include <hip/hip_runtime.h>

// SKA: per-pixel dynamic grouped 3x3 conv.
// x: [B=16, C=128, H=56, W=56] f32
// w: [B=16, Cw=16, 9, H=56, W=56] f32   (channel c uses weight channel c % 16)
// out[b,c,h,w] = sum_{i,j} xpad[b,c,h+i,w+j] * w[b, c%16, i*3+j, h, w], pad=1.
//
// Round 8 (= round 7 + compile fix): LDS tile with CPB=2 -> 31.5KB LDS ->
// 4 blocks/CU (16 waves/CU) so stage/compute phases of different blocks
// overlap. 1024 blocks; 4 blocks share each w panel (L2/L3 dedup).
// Nontemporal f4 output stores via native ext_vector type (HIP float4 is a
// class type that __builtin_nontemporal_store rejects).

#define SKA_B   16
#define SKA_C   128
#define SKA_CW  16
#define SKA_H   56
#define SKA_W   56
#define SKA_HW  (SKA_H * SKA_W)        // 3136
#define CPB     2                      // channels per block
#define SKA_GS  4                      // group-split: blocks per (b,cw)
#define LROWS   58                     // 56 + top/bottom halo
#define LSTRIDE 68                     // 4-col left halo + 56 + pad; rows 16B-aligned
#define LSLOTS  (CPB * LROWS * LSTRIDE / 4)  // float4 slots = 31,552 B total

typedef float f32x4 __attribute__((ext_vector_type(4)));

__global__ __launch_bounds__(256) void ska_kernel(
    const float* __restrict__ x,
    const float* __restrict__ w,
    float* __restrict__ out)
{
    __shared__ float lds[CPB][LROWS][LSTRIDE];

    const int tid = threadIdx.x;
    const int blk = blockIdx.x;        // 0..1023
    const int gs  = blk & 3;           // channels g = gs*2, gs*2+1
    const int cwb = blk >> 2;
    const int cw  = cwb & 15;
    const int b   = cwb >> 4;

    // Phase 0: zero all of LDS (halo included). ~8 f4 stores/thread.
    {
        const float4 z = {0.f, 0.f, 0.f, 0.f};
        float4* lf4 = (float4*)&lds[0][0][0];
        for (int i = tid; i < LSLOTS; i += 256) lf4[i] = z;
    }
    __syncthreads();

    // Phase 1: stage x rows. Channel c = (gs*2 + ch)*16 + cw.
    // x row h -> lds row h+1, x col c -> lds col c+4. All float4-aligned.
    const float* xb = x + ((size_t)b * SKA_C + (size_t)gs * CPB * SKA_CW + cw) * SKA_HW;
    for (int i = tid; i < CPB * SKA_H * 14; i += 256) {   // 1568 float4 loads
        const int q  = i % 14;
        const int t  = i / 14;
        const int h  = t % SKA_H;
        const int ch = t / SKA_H;
        const float4 v = *(const float4*)(xb + (size_t)ch * SKA_CW * SKA_HW + h * SKA_W + 4 * q);
        *(float4*)&lds[ch][h + 1][4 * q + 4] = v;
    }
    __syncthreads();

    // Phase 2: compute. Thread handles pixel-quads (h, q) for both channels.
    const float* wb = w + ((size_t)(b * SKA_CW + cw) * 9) * SKA_HW;
    float* ob = out + ((size_t)b * SKA_C + (size_t)gs * CPB * SKA_CW + cw) * SKA_HW;

    for (int i = tid; i < SKA_H * 14; i += 256) {         // 784 pixel-quads
        const int q  = i % 14;
        const int h  = i / 14;
        const int hw = h * SKA_W + 4 * q;

        // 9 per-pixel weight vectors, shared by the block's channels.
        float4 wk[9];
#pragma unroll
        for (int k = 0; k < 9; ++k)
            wk[k] = *(const float4*)(wb + (size_t)k * SKA_HW + hw);

#pragma unroll
        for (int ch = 0; ch < CPB; ++ch) {
            float a0 = 0.f, a1 = 0.f, a2 = 0.f, a3 = 0.f;
#pragma unroll
            for (int r = 0; r < 3; ++r) {
                // Output row h uses x rows h-1..h+1 -> lds rows h..h+2.
                const float* lp = &lds[ch][h + r][4 * q + 2];
                const float2 dl = *(const float2*)lp;        // cols +2,+3
                const float4 m  = *(const float4*)(lp + 2);  // cols +4..+7
                const float  e  = lp[6];                     // col  +8
                const float4 w0 = wk[3 * r + 0];
                const float4 w1 = wk[3 * r + 1];
                const float4 w2 = wk[3 * r + 2];
                a0 += dl.y * w0.x + m.x * w1.x + m.y * w2.x;
                a1 += m.x  * w0.y + m.y * w1.y + m.z * w2.y;
                a2 += m.y  * w0.z + m.z * w1.z + m.w * w2.z;
                a3 += m.z  * w0.w + m.w * w1.w + e   * w2.w;
            }
            f32x4 o = {a0, a1, a2, a3};
            __builtin_nontemporal_store(o, (f32x4*)(ob + (size_t)ch * SKA_CW * SKA_HW + hw));
        }
    }
}

extern "C" void kernel_launch(void* const* d_in, const int* in_sizes, int n_in,
                              void* d_out, int out_size, void* d_ws, size_t ws_size,
                              hipStream_t stream) {
    const float* x = (const float*)d_in[0];
    const float* w = (const float*)d_in[1];
    float* out = (float*)d_out;

    const int grid = SKA_B * SKA_CW * SKA_GS;   // 1024 blocks = 4 per CU
    ska_kernel<<<grid, 256, 0, stream>>>(x, w, out);
}